// Round 18
// baseline (476.178 us; speedup 1.0000x reference)
//
#include <hip/hip_runtime.h>

#define HW 512
#define NSTATE (HW * HW)   // 262144
#define NC4_X 196608       // x as float4 (3*H*W/4)
#define NC4_POLROW 262144  // Wpol row stride in float4 (4 MiB)
#define NC4_V 65536        // v as float4

#define CH4 1024   // float4 per wave-chunk (16 KB)
#define NCH_X 192  // chunks per W1 row
#define SPAN_ROP 1024

// ws layout (float offsets)
#define WS_PART1 0      // 192*32 = 6144
#define WS_PARTP 6144   // 256*32 = 8192
#define WS_P 14400      // 262144
#define WS_RD (WS_P + NSTATE)
#define WS_V (WS_RD + NSTATE)
#define WS_CNT 1048576  // 4-byte atomic counter (memset to 0 every call)

#define SGB __builtin_amdgcn_sched_group_barrier

__device__ __forceinline__ float wred(float a) {
  a += __shfl_xor(a, 32);
  a += __shfl_xor(a, 16);
  a += __shfl_xor(a, 8);
  a += __shfl_xor(a, 4);
  a += __shfl_xor(a, 2);
  a += __shfl_xor(a, 1);
  return a;
}

__device__ __forceinline__ float span_dot(const float4* __restrict__ wp,
                                          const float4* __restrict__ xp) {
  float acc = 0.f;
#pragma unroll
  for (int bt = 0; bt < 2; ++bt) {
    float4 w[8], xv[8];
#pragma unroll
    for (int j = 0; j < 8; ++j) w[j] = wp[bt * 512 + j * 64];
#pragma unroll
    for (int j = 0; j < 8; ++j) xv[j] = xp[bt * 512 + j * 64];
    SGB(0x020, 16, 0);
#pragma unroll
    for (int j = 0; j < 8; ++j)
      acc += w[j].x * xv[j].x + w[j].y * xv[j].y + w[j].z * xv[j].z +
             w[j].w * xv[j].w;
  }
  return acc;
}

// ---------------------------------------------------------------------------
// K1: W1@x partials, flat-linear (~15 µs, at floor). 1536 blocks.
// ---------------------------------------------------------------------------
__global__ __launch_bounds__(256) void mv_w1(const float4* __restrict__ W1,
                                             const float4* __restrict__ x,
                                             float* __restrict__ part1) {
  int b = blockIdx.x;
  int row = b / 48, cb = b - row * 48;
  int tid = threadIdx.x, wave = tid >> 6, lane = tid & 63;
  int ch = cb * 4 + wave;
  const float4* __restrict__ wp =
      W1 + (size_t)row * NC4_X + (size_t)ch * CH4 + lane;
  const float4* __restrict__ xp = x + (size_t)ch * CH4 + lane;
  float acc = span_dot(wp, xp);
  acc = wred(acc);
  if (lane == 0) part1[ch * 32 + row] = acc;
}

// ---------------------------------------------------------------------------
// K2: rop with finish_h folded in as a redundant per-block prologue (R18):
// every block reduces part1 (24 KB, L2-hot) -> h1 -> h2 in LDS, then runs
// the unchanged R5 rop body with h4 read from LDS. Removes the 1-block
// finish_h dispatch + a launch boundary from the serial chain.
// ---------------------------------------------------------------------------
__global__ __launch_bounds__(256) void rop_h(
    const float* __restrict__ part1, const float* __restrict__ b1,
    const float* __restrict__ W2, const float* __restrict__ b2,
    const float4* __restrict__ Wro4, const float* __restrict__ bro,
    const float4* __restrict__ Wri4, const float* __restrict__ bri,
    const float4* __restrict__ Wp4, const float* __restrict__ bp,
    float* __restrict__ p_out, float* __restrict__ rd_out) {
  __shared__ float red[8][32];
  __shared__ float h1s[32];
  __shared__ float h2s[64];
  __shared__ float dots[4][3][64];
  int tid = threadIdx.x;
  int wave = tid >> 6, lane = tid & 63;
  // --- finish_h prologue (block-local, redundant across blocks) ---
  {
    int r = tid & 31, g = tid >> 5;
    float s = 0.f;
    for (int b = g; b < NCH_X; b += 8) s += part1[b * 32 + r];
    red[g][r] = s;
  }
  __syncthreads();
  if (tid < 32) {
    float t = b1[tid];
    for (int g = 0; g < 8; ++g) t += red[g][tid];
    h1s[tid] = fmaxf(t, 0.f);
  }
  __syncthreads();
  if (tid < 64) {
    float t = b2[tid];
    for (int k = 0; k < 32; ++k) t += W2[tid * 32 + k] * h1s[k];
    h2s[tid] = fmaxf(t, 0.f);
  }
  __syncthreads();
  // --- rop body (R5, unchanged except h4 from LDS) ---
  int grp = lane >> 4;
  float4 h4 = ((const float4*)h2s)[lane & 15];
  int span = blockIdx.x * 4 + wave;
  size_t base = (size_t)span * SPAN_ROP;
  const float4* mats[3] = {Wro4, Wri4, Wp4};
#pragma unroll
  for (int m = 0; m < 3; ++m) {
    const float4* __restrict__ W = mats[m] + base + lane;
#pragma unroll
    for (int batch = 0; batch < 2; ++batch) {
      float4 w[8];
#pragma unroll
      for (int j = 0; j < 8; ++j) w[j] = W[(batch * 8 + j) * 64];
      SGB(0x020, 8, 0);
      float part[8];
#pragma unroll
      for (int j = 0; j < 8; ++j)
        part[j] = w[j].x * h4.x + w[j].y * h4.y + w[j].z * h4.z + w[j].w * h4.w;
#pragma unroll
      for (int j = 0; j < 8; ++j) {
        part[j] += __shfl_xor(part[j], 8);
        part[j] += __shfl_xor(part[j], 4);
        part[j] += __shfl_xor(part[j], 2);
        part[j] += __shfl_xor(part[j], 1);
      }
      if ((lane & 15) == 0) {
#pragma unroll
        for (int j = 0; j < 8; ++j)
          dots[wave][m][(batch * 8 + j) * 4 + grp] = part[j];
      }
    }
  }
  __syncthreads();
  int o = blockIdx.x * 256 + tid;
  float dro = dots[tid >> 6][0][tid & 63] + bro[o];
  float dri = dots[tid >> 6][1][tid & 63] + bri[o];
  float dp = dots[tid >> 6][2][tid & 63] + bp[o];
  float sro = 1.f / (1.f + __expf(-dro));
  float sri = 1.f / (1.f + __expf(-dri));
  float pv = 1.f / (1.f + __expf(-dp));
  p_out[o] = pv;
  rd_out[o] = sri - sro;
}

// ---------------------------------------------------------------------------
// K3: valiter (R17 rewrite, measured-good: one barrier/iter, float4 LDS,
// p/rd in registers, shrinking active region). 1024 blocks x 384 threads.
// ---------------------------------------------------------------------------
#define VTILE 16
#define VHALO 10
#define ULW 44
#define ULH 38
__device__ __forceinline__ void row_win(const float* __restrict__ r,
                                        float e[6]) {
  float4 L = *reinterpret_cast<const float4*>(r - 4);
  float4 M = *reinterpret_cast<const float4*>(r);
  float4 R = *reinterpret_cast<const float4*>(r + 4);
  e[0] = L.w; e[1] = M.x; e[2] = M.y; e[3] = M.z; e[4] = M.w; e[5] = R.x;
}
__global__ __launch_bounds__(384) void valiter_kernel(
    const float* __restrict__ p, const float* __restrict__ rd,
    float* __restrict__ vout) {
  __shared__ float ua[ULH * ULW];
  __shared__ float ub[ULH * ULW];
  int tid = threadIdx.x;
  int blk = blockIdx.x;
  int ti = blk >> 5, tj = blk & 31;
  for (int idx = tid; idx < ULH * ULW; idx += 384) {
    ua[idx] = 0.f;
    ub[idx] = 0.f;
  }
  int i = tid / 9, j4 = tid - i * 9;
  bool active = (i < 36);
  int cb = 4 + 4 * j4;
  float pp[4], rr[4];
  if (active) {
    int gi = ti * VTILE - VHALO + i;
    int gj0 = tj * VTILE - VHALO + 4 * j4;
#pragma unroll
    for (int k = 0; k < 4; ++k) {
      int gj = gj0 + k;
      bool ok = (gi >= 0) & (gi < HW) & (gj >= 0) & (gj < HW);
      int gidx = gi * HW + gj;
      pp[k] = ok ? p[gidx] : 0.f;
      rr[k] = ok ? rd[gidx] : 0.f;
    }
  }
  __syncthreads();
  if (active) {
    *reinterpret_cast<float4*>(&ua[(i + 1) * ULW + cb]) =
        make_float4(rr[0], rr[1], rr[2], rr[3]);
  }
  __syncthreads();
  float* src = ua;
  float* dst = ub;
  for (int q = 0; q < 9; ++q) {
    int lo = q + 1, hi = 35 - q;
    if (active && i >= lo && i < hi && (4 * j4 + 4) > lo && (4 * j4) < hi) {
      float eA[6], eB[6], eC[6];
      row_win(src + i * ULW + cb, eA);
      row_win(src + (i + 1) * ULW + cb, eB);
      row_win(src + (i + 2) * ULW + cb, eC);
      float res[4];
#pragma unroll
      for (int k = 0; k < 4; ++k) {
        float a = fmaxf(fmaxf(eA[k], eA[k + 1]), eA[k + 2]);
        float c = fmaxf(fmaxf(eC[k], eC[k + 1]), eC[k + 2]);
        float b = fmaxf(eB[k], eB[k + 2]);
        float m = fmaxf(fmaxf(a, c), b);
        res[k] = m * pp[k] + rr[k];
      }
      *reinterpret_cast<float4*>(&dst[(i + 1) * ULW + cb]) =
          make_float4(res[0], res[1], res[2], res[3]);
    }
    __syncthreads();
    float* t_ = src;
    src = dst;
    dst = t_;
  }
  if (active && i >= 10 && i < 26 && (4 * j4 + 4) > 10 && (4 * j4) < 26) {
    float eA[6], eB[6], eC[6];
    row_win(src + i * ULW + cb, eA);
    row_win(src + (i + 1) * ULW + cb, eB);
    row_win(src + (i + 2) * ULW + cb, eC);
#pragma unroll
    for (int k = 0; k < 4; ++k) {
      int cj = 4 * j4 + k;
      if (cj >= 10 && cj < 26) {
        float a = fmaxf(fmaxf(eA[k], eA[k + 1]), eA[k + 2]);
        float c = fmaxf(fmaxf(eC[k], eC[k + 1]), eC[k + 2]);
        float b = fmaxf(eB[k], eB[k + 2]);
        float m = fmaxf(fmaxf(a, c), b);
        vout[(ti * VTILE + i - 10) * HW + tj * VTILE + cj - 10] = m;
      }
    }
  }
}

// ---------------------------------------------------------------------------
// K4: mv_pol (flat whole-Wpol sweep) with finish_pol folded in via the
// atomic-tail pattern: each block fences + increments cnt; the 2048th block
// reduces partP and runs heads+softmax+v[pos]. Reduction order is fixed by
// code -> values identical regardless of which block is last (deterministic).
// cnt is zeroed every call by a 4-byte hipMemsetAsync before the chain.
// ---------------------------------------------------------------------------
__global__ __launch_bounds__(256) void mv_pol_fin(
    const float4* __restrict__ Wpol, const float4* __restrict__ x,
    const float4* __restrict__ v, float* __restrict__ partP,
    const float* __restrict__ bpol, const float* __restrict__ Whead,
    const float* __restrict__ bhead, const float* __restrict__ vflat,
    const int* __restrict__ pos, float* __restrict__ out,
    unsigned int* __restrict__ cnt) {
  int b = blockIdx.x;
  int tid = threadIdx.x, wave = tid >> 6, lane = tid & 63;
  int f = b * 4 + wave;
  int row = f >> 8, rc = f & 255;
  const float4* __restrict__ wp = Wpol + (size_t)f * CH4 + lane;
  const float4* __restrict__ xp =
      (rc < 64) ? (v + (size_t)rc * CH4 + lane)
                : (x + (size_t)(rc - 64) * CH4 + lane);
  float acc = span_dot(wp, xp);
  acc = wred(acc);
  if (lane == 0) partP[rc * 32 + row] = acc;
  // --- atomic-tail finish_pol ---
  __threadfence();  // make this block's partials visible device-wide
  __shared__ unsigned int done;
  if (tid == 0) done = atomicAdd(cnt, 1u);
  __syncthreads();
  if (done == 2047u) {  // last block: all partials visible
    __shared__ float red[8][32];
    __shared__ float hp[32];
    __shared__ float logits[8];
    int r = tid & 31, g = tid >> 5;
    float s = 0.f;
    for (int bb = g; bb < 256; bb += 8) s += partP[bb * 32 + r];
    red[g][r] = s;
    __syncthreads();
    if (tid < 32) {
      float t = bpol[tid];
      for (int gg = 0; gg < 8; ++gg) t += red[gg][tid];
      hp[tid] = fmaxf(t, 0.f);
    }
    __syncthreads();
    if (tid < 8) {
      float t = bhead[tid];
      for (int k = 0; k < 32; ++k) t += Whead[tid * 32 + k] * hp[k];
      logits[tid] = t;
    }
    __syncthreads();
    if (tid == 0) {
      float mx = logits[0];
      for (int j = 1; j < 8; ++j) mx = fmaxf(mx, logits[j]);
      float e[8], sum = 0.f;
      for (int j = 0; j < 8; ++j) {
        e[j] = __expf(logits[j] - mx);
        sum += e[j];
      }
      for (int j = 0; j < 8; ++j) out[j] = e[j] / sum;
      out[8] = vflat[pos[0] * HW + pos[1]];
    }
  }
}

extern "C" void kernel_launch(void* const* d_in, const int* in_sizes, int n_in,
                              void* d_out, int out_size, void* d_ws,
                              size_t ws_size, hipStream_t stream) {
  const float* x = (const float*)d_in[0];
  const int* pos = (const int*)d_in[1];
  const float* W1 = (const float*)d_in[2];
  const float* b1 = (const float*)d_in[3];
  const float* W2 = (const float*)d_in[4];
  const float* b2 = (const float*)d_in[5];
  const float* Wro = (const float*)d_in[6];
  const float* bro = (const float*)d_in[7];
  const float* Wri = (const float*)d_in[8];
  const float* bri = (const float*)d_in[9];
  const float* Wp = (const float*)d_in[10];
  const float* bp = (const float*)d_in[11];
  const float* Wpol = (const float*)d_in[12];
  const float* bpol = (const float*)d_in[13];
  const float* Whead = (const float*)d_in[14];
  const float* bhead = (const float*)d_in[15];
  float* ws = (float*)d_ws;
  float* out = (float*)d_out;

  float* part1 = ws + WS_PART1;
  float* partP = ws + WS_PARTP;
  float* pbuf = ws + WS_P;
  float* rdbuf = ws + WS_RD;
  float* vbuf = ws + WS_V;
  unsigned int* cnt = (unsigned int*)(ws + WS_CNT);

  // zero the atomic counter (graph-capturable, deterministic every call)
  hipMemsetAsync(cnt, 0, sizeof(unsigned int), stream);

  // K1: W1@x partials
  mv_w1<<<1536, 256, 0, stream>>>((const float4*)W1, (const float4*)x, part1);
  // K2: h1->h2 (per-block) + rop
  rop_h<<<1024, 256, 0, stream>>>(part1, b1, W2, b2, (const float4*)Wro, bro,
                                  (const float4*)Wri, bri, (const float4*)Wp,
                                  bp, pbuf, rdbuf);
  // K3: 10 value-iteration steps
  valiter_kernel<<<1024, 384, 0, stream>>>(pbuf, rdbuf, vbuf);
  // K4: all Wpol partials + atomic-tail heads/softmax
  mv_pol_fin<<<2048, 256, 0, stream>>>((const float4*)Wpol, (const float4*)x,
                                       (const float4*)vbuf, partP, bpol, Whead,
                                       bhead, vbuf, pos, out, cnt);
}

// Round 19
// 112.031 us; speedup vs baseline: 4.2504x; 4.2504x over previous
//
#include <hip/hip_runtime.h>

#define HW 512
#define NSTATE (HW * HW)   // 262144
#define NC4_X 196608       // x as float4 (3*H*W/4)
#define NC4_POLROW 262144  // Wpol row stride in float4 (4 MiB)
#define NC4_V 65536        // v as float4

#define CH4 1024   // float4 per wave-chunk (16 KB)
#define NCH_X 192  // chunks per W1 row
#define SPAN_ROP 1024

// ws layout (float offsets)
#define WS_PART1 0      // 192*32 = 6144
#define WS_PARTP 6144   // 256*32 = 8192
#define WS_P 14400      // 262144
#define WS_RD (WS_P + NSTATE)
#define WS_V (WS_RD + NSTATE)

#define SGB __builtin_amdgcn_sched_group_barrier

__device__ __forceinline__ float wred(float a) {
  a += __shfl_xor(a, 32);
  a += __shfl_xor(a, 16);
  a += __shfl_xor(a, 8);
  a += __shfl_xor(a, 4);
  a += __shfl_xor(a, 2);
  a += __shfl_xor(a, 1);
  return a;
}

__device__ __forceinline__ float span_dot(const float4* __restrict__ wp,
                                          const float4* __restrict__ xp) {
  float acc = 0.f;
#pragma unroll
  for (int bt = 0; bt < 2; ++bt) {
    float4 w[8], xv[8];
#pragma unroll
    for (int j = 0; j < 8; ++j) w[j] = wp[bt * 512 + j * 64];
#pragma unroll
    for (int j = 0; j < 8; ++j) xv[j] = xp[bt * 512 + j * 64];
    SGB(0x020, 16, 0);
#pragma unroll
    for (int j = 0; j < 8; ++j)
      acc += w[j].x * xv[j].x + w[j].y * xv[j].y + w[j].z * xv[j].z +
             w[j].w * xv[j].w;
  }
  return acc;
}

// ---------------------------------------------------------------------------
// K1: W1@x partials, flat-linear (~15 µs, at floor). 1536 blocks.
// ---------------------------------------------------------------------------
__global__ __launch_bounds__(256) void mv_w1(const float4* __restrict__ W1,
                                             const float4* __restrict__ x,
                                             float* __restrict__ part1) {
  int b = blockIdx.x;
  int row = b / 48, cb = b - row * 48;
  int tid = threadIdx.x, wave = tid >> 6, lane = tid & 63;
  int ch = cb * 4 + wave;
  const float4* __restrict__ wp =
      W1 + (size_t)row * NC4_X + (size_t)ch * CH4 + lane;
  const float4* __restrict__ xp = x + (size_t)ch * CH4 + lane;
  float acc = span_dot(wp, xp);
  acc = wred(acc);
  if (lane == 0) part1[ch * 32 + row] = acc;
}

// ---------------------------------------------------------------------------
// K2: rop with finish_h folded in as a redundant per-block prologue (R18,
// proven safe: stayed under cutoff): every block reduces part1 (24 KB,
// L2-hot) -> h1 -> h2 in LDS, then runs the R5 rop body with h4 from LDS.
// R18 lesson kept OUT: no device-scope fences anywhere (the atomic-tail
// fusion cost 400 µs — 2048 L2-writeback fences on non-coherent XCD L2s).
// ---------------------------------------------------------------------------
__global__ __launch_bounds__(256) void rop_h(
    const float* __restrict__ part1, const float* __restrict__ b1,
    const float* __restrict__ W2, const float* __restrict__ b2,
    const float4* __restrict__ Wro4, const float* __restrict__ bro,
    const float4* __restrict__ Wri4, const float* __restrict__ bri,
    const float4* __restrict__ Wp4, const float* __restrict__ bp,
    float* __restrict__ p_out, float* __restrict__ rd_out) {
  __shared__ float red[8][32];
  __shared__ float h1s[32];
  __shared__ float h2s[64];
  __shared__ float dots[4][3][64];
  int tid = threadIdx.x;
  int wave = tid >> 6, lane = tid & 63;
  {
    int r = tid & 31, g = tid >> 5;
    float s = 0.f;
    for (int b = g; b < NCH_X; b += 8) s += part1[b * 32 + r];
    red[g][r] = s;
  }
  __syncthreads();
  if (tid < 32) {
    float t = b1[tid];
    for (int g = 0; g < 8; ++g) t += red[g][tid];
    h1s[tid] = fmaxf(t, 0.f);
  }
  __syncthreads();
  if (tid < 64) {
    float t = b2[tid];
    for (int k = 0; k < 32; ++k) t += W2[tid * 32 + k] * h1s[k];
    h2s[tid] = fmaxf(t, 0.f);
  }
  __syncthreads();
  int grp = lane >> 4;
  float4 h4 = ((const float4*)h2s)[lane & 15];
  int span = blockIdx.x * 4 + wave;
  size_t base = (size_t)span * SPAN_ROP;
  const float4* mats[3] = {Wro4, Wri4, Wp4};
#pragma unroll
  for (int m = 0; m < 3; ++m) {
    const float4* __restrict__ W = mats[m] + base + lane;
#pragma unroll
    for (int batch = 0; batch < 2; ++batch) {
      float4 w[8];
#pragma unroll
      for (int j = 0; j < 8; ++j) w[j] = W[(batch * 8 + j) * 64];
      SGB(0x020, 8, 0);
      float part[8];
#pragma unroll
      for (int j = 0; j < 8; ++j)
        part[j] = w[j].x * h4.x + w[j].y * h4.y + w[j].z * h4.z + w[j].w * h4.w;
#pragma unroll
      for (int j = 0; j < 8; ++j) {
        part[j] += __shfl_xor(part[j], 8);
        part[j] += __shfl_xor(part[j], 4);
        part[j] += __shfl_xor(part[j], 2);
        part[j] += __shfl_xor(part[j], 1);
      }
      if ((lane & 15) == 0) {
#pragma unroll
        for (int j = 0; j < 8; ++j)
          dots[wave][m][(batch * 8 + j) * 4 + grp] = part[j];
      }
    }
  }
  __syncthreads();
  int o = blockIdx.x * 256 + tid;
  float dro = dots[tid >> 6][0][tid & 63] + bro[o];
  float dri = dots[tid >> 6][1][tid & 63] + bri[o];
  float dp = dots[tid >> 6][2][tid & 63] + bp[o];
  float sro = 1.f / (1.f + __expf(-dro));
  float sri = 1.f / (1.f + __expf(-dri));
  float pv = 1.f / (1.f + __expf(-dp));
  p_out[o] = pv;
  rd_out[o] = sri - sro;
}

// ---------------------------------------------------------------------------
// K3: valiter (R17 rewrite: one barrier/iter, float4 LDS, p/rd in registers,
// shrinking active region). 1024 blocks x 384 threads. ~9 µs.
// ---------------------------------------------------------------------------
#define VTILE 16
#define VHALO 10
#define ULW 44
#define ULH 38
__device__ __forceinline__ void row_win(const float* __restrict__ r,
                                        float e[6]) {
  float4 L = *reinterpret_cast<const float4*>(r - 4);
  float4 M = *reinterpret_cast<const float4*>(r);
  float4 R = *reinterpret_cast<const float4*>(r + 4);
  e[0] = L.w; e[1] = M.x; e[2] = M.y; e[3] = M.z; e[4] = M.w; e[5] = R.x;
}
__global__ __launch_bounds__(384) void valiter_kernel(
    const float* __restrict__ p, const float* __restrict__ rd,
    float* __restrict__ vout) {
  __shared__ float ua[ULH * ULW];
  __shared__ float ub[ULH * ULW];
  int tid = threadIdx.x;
  int blk = blockIdx.x;
  int ti = blk >> 5, tj = blk & 31;
  for (int idx = tid; idx < ULH * ULW; idx += 384) {
    ua[idx] = 0.f;
    ub[idx] = 0.f;
  }
  int i = tid / 9, j4 = tid - i * 9;
  bool active = (i < 36);
  int cb = 4 + 4 * j4;
  float pp[4], rr[4];
  if (active) {
    int gi = ti * VTILE - VHALO + i;
    int gj0 = tj * VTILE - VHALO + 4 * j4;
#pragma unroll
    for (int k = 0; k < 4; ++k) {
      int gj = gj0 + k;
      bool ok = (gi >= 0) & (gi < HW) & (gj >= 0) & (gj < HW);
      int gidx = gi * HW + gj;
      pp[k] = ok ? p[gidx] : 0.f;
      rr[k] = ok ? rd[gidx] : 0.f;
    }
  }
  __syncthreads();
  if (active) {
    *reinterpret_cast<float4*>(&ua[(i + 1) * ULW + cb]) =
        make_float4(rr[0], rr[1], rr[2], rr[3]);
  }
  __syncthreads();
  float* src = ua;
  float* dst = ub;
  for (int q = 0; q < 9; ++q) {
    int lo = q + 1, hi = 35 - q;
    if (active && i >= lo && i < hi && (4 * j4 + 4) > lo && (4 * j4) < hi) {
      float eA[6], eB[6], eC[6];
      row_win(src + i * ULW + cb, eA);
      row_win(src + (i + 1) * ULW + cb, eB);
      row_win(src + (i + 2) * ULW + cb, eC);
      float res[4];
#pragma unroll
      for (int k = 0; k < 4; ++k) {
        float a = fmaxf(fmaxf(eA[k], eA[k + 1]), eA[k + 2]);
        float c = fmaxf(fmaxf(eC[k], eC[k + 1]), eC[k + 2]);
        float b = fmaxf(eB[k], eB[k + 2]);
        float m = fmaxf(fmaxf(a, c), b);
        res[k] = m * pp[k] + rr[k];
      }
      *reinterpret_cast<float4*>(&dst[(i + 1) * ULW + cb]) =
          make_float4(res[0], res[1], res[2], res[3]);
    }
    __syncthreads();
    float* t_ = src;
    src = dst;
    dst = t_;
  }
  if (active && i >= 10 && i < 26 && (4 * j4 + 4) > 10 && (4 * j4) < 26) {
    float eA[6], eB[6], eC[6];
    row_win(src + i * ULW + cb, eA);
    row_win(src + (i + 1) * ULW + cb, eB);
    row_win(src + (i + 2) * ULW + cb, eC);
#pragma unroll
    for (int k = 0; k < 4; ++k) {
      int cj = 4 * j4 + k;
      if (cj >= 10 && cj < 26) {
        float a = fmaxf(fmaxf(eA[k], eA[k + 1]), eA[k + 2]);
        float c = fmaxf(fmaxf(eC[k], eC[k + 1]), eC[k + 2]);
        float b = fmaxf(eB[k], eB[k + 2]);
        float m = fmaxf(fmaxf(a, c), b);
        vout[(ti * VTILE + i - 10) * HW + tj * VTILE + cj - 10] = m;
      }
    }
  }
}

// ---------------------------------------------------------------------------
// K4: all Wpol in one flat sweep (~15-18 µs, no fences, no atomics).
// ---------------------------------------------------------------------------
__global__ __launch_bounds__(256) void mv_pol(const float4* __restrict__ Wpol,
                                              const float4* __restrict__ x,
                                              const float4* __restrict__ v,
                                              float* __restrict__ partP) {
  int b = blockIdx.x;
  int tid = threadIdx.x, wave = tid >> 6, lane = tid & 63;
  int f = b * 4 + wave;
  int row = f >> 8, rc = f & 255;
  const float4* __restrict__ wp = Wpol + (size_t)f * CH4 + lane;
  const float4* __restrict__ xp =
      (rc < 64) ? (v + (size_t)rc * CH4 + lane)
                : (x + (size_t)(rc - 64) * CH4 + lane);
  float acc = span_dot(wp, xp);
  acc = wred(acc);
  if (lane == 0) partP[rc * 32 + row] = acc;
}

// ---------------------------------------------------------------------------
// K5: finish_pol (1 block; launch-boundary provides the visibility the
// fence-based fusion tried and failed to provide cheaply).
// ---------------------------------------------------------------------------
__global__ __launch_bounds__(1024) void finish_pol(
    const float* __restrict__ partP, const float* __restrict__ bpol,
    const float* __restrict__ Whead, const float* __restrict__ bhead,
    const float* __restrict__ v, const int* __restrict__ pos,
    float* __restrict__ out) {
  __shared__ float red[32][32];
  __shared__ float hp[32];
  __shared__ float logits[8];
  int tid = threadIdx.x;
  int row = tid & 31, grp = tid >> 5;
  float s = 0.f;
  for (int b = grp; b < 256; b += 32) s += partP[b * 32 + row];
  red[grp][row] = s;
  __syncthreads();
  if (tid < 32) {
    float t = bpol[tid];
    for (int g = 0; g < 32; ++g) t += red[g][tid];
    hp[tid] = fmaxf(t, 0.f);
  }
  __syncthreads();
  if (tid < 8) {
    float t = bhead[tid];
    for (int k = 0; k < 32; ++k) t += Whead[tid * 32 + k] * hp[k];
    logits[tid] = t;
  }
  __syncthreads();
  if (tid == 0) {
    float mx = logits[0];
    for (int j = 1; j < 8; ++j) mx = fmaxf(mx, logits[j]);
    float e[8], sum = 0.f;
    for (int j = 0; j < 8; ++j) {
      e[j] = __expf(logits[j] - mx);
      sum += e[j];
    }
    for (int j = 0; j < 8; ++j) out[j] = e[j] / sum;
    out[8] = v[pos[0] * HW + pos[1]];
  }
}

extern "C" void kernel_launch(void* const* d_in, const int* in_sizes, int n_in,
                              void* d_out, int out_size, void* d_ws,
                              size_t ws_size, hipStream_t stream) {
  const float* x = (const float*)d_in[0];
  const int* pos = (const int*)d_in[1];
  const float* W1 = (const float*)d_in[2];
  const float* b1 = (const float*)d_in[3];
  const float* W2 = (const float*)d_in[4];
  const float* b2 = (const float*)d_in[5];
  const float* Wro = (const float*)d_in[6];
  const float* bro = (const float*)d_in[7];
  const float* Wri = (const float*)d_in[8];
  const float* bri = (const float*)d_in[9];
  const float* Wp = (const float*)d_in[10];
  const float* bp = (const float*)d_in[11];
  const float* Wpol = (const float*)d_in[12];
  const float* bpol = (const float*)d_in[13];
  const float* Whead = (const float*)d_in[14];
  const float* bhead = (const float*)d_in[15];
  float* ws = (float*)d_ws;
  float* out = (float*)d_out;

  float* part1 = ws + WS_PART1;
  float* partP = ws + WS_PARTP;
  float* pbuf = ws + WS_P;
  float* rdbuf = ws + WS_RD;
  float* vbuf = ws + WS_V;

  // K1: W1@x partials
  mv_w1<<<1536, 256, 0, stream>>>((const float4*)W1, (const float4*)x, part1);
  // K2: h1->h2 (per-block prologue) + rop
  rop_h<<<1024, 256, 0, stream>>>(part1, b1, W2, b2, (const float4*)Wro, bro,
                                  (const float4*)Wri, bri, (const float4*)Wp,
                                  bp, pbuf, rdbuf);
  // K3: 10 value-iteration steps
  valiter_kernel<<<1024, 384, 0, stream>>>(pbuf, rdbuf, vbuf);
  // K4: all Wpol partials
  mv_pol<<<2048, 256, 0, stream>>>((const float4*)Wpol, (const float4*)x,
                                   (const float4*)vbuf, partP);
  // K5: heads + softmax + state value
  finish_pol<<<1, 1024, 0, stream>>>(partP, bpol, Whead, bhead, vbuf, pos,
                                     out);
}